// Round 8
// baseline (860.659 us; speedup 1.0000x reference)
//
#include <hip/hip_runtime.h>
#include <hip/hip_bf16.h>
#include <math.h>

#define NSRC 8192
#define NTGT 8192
#define DIM 64

typedef short bf16x8 __attribute__((ext_vector_type(8)));
typedef float f32x16 __attribute__((ext_vector_type(16)));

// ---------------------------------------------------------------------------
// helpers
// ---------------------------------------------------------------------------
__device__ __forceinline__ float wave_reduce_sum(float x) {
#pragma unroll
  for (int off = 32; off > 0; off >>= 1) x += __shfl_down(x, off, 64);
  return x;
}

__device__ __forceinline__ float bflo(unsigned int u) {  // low bf16 of a u32
  return __uint_as_float(u << 16);
}
__device__ __forceinline__ float bfhi(unsigned int u) {  // high bf16 of a u32
  return __uint_as_float(u & 0xFFFF0000u);
}
__device__ __forceinline__ unsigned short f2bfr(float x) {
  __hip_bfloat16 b = __float2bfloat16(x);
  return __hip_bfloat16_raw(b).x;
}

// ---------------------------------------------------------------------------
// kernel 1: squared norms of source rows and target rows (f32 inputs)
// ---------------------------------------------------------------------------
__global__ __launch_bounds__(256) void norms_k(const float* __restrict__ S,
                                               const float* __restrict__ T,
                                               float* __restrict__ s2,
                                               float* __restrict__ t2) {
  int i = blockIdx.x * 256 + threadIdx.x;
  if (i >= NSRC + NTGT) return;
  const float* base = (i < NSRC) ? (S + (size_t)i * DIM)
                                 : (T + (size_t)(i - NSRC) * DIM);
  const float4* p = (const float4*)base;
  float a = 0.f;
#pragma unroll
  for (int k = 0; k < DIM / 4; ++k) {
    float4 v = p[k];
    a += v.x * v.x + v.y * v.y + v.z * v.z + v.w * v.w;
  }
  if (i < NSRC) s2[i] = a;
  else          t2[i - NSRC] = a;
}

// ---------------------------------------------------------------------------
// kernel 1b: split features into bf16 hi + bf16 lo (lo = x - float(hi)).
// ---------------------------------------------------------------------------
__global__ __launch_bounds__(256) void prep_k(const float* __restrict__ S,
                                              const float* __restrict__ T,
                                              unsigned short* __restrict__ Shi,
                                              unsigned short* __restrict__ Slo,
                                              unsigned short* __restrict__ Thi,
                                              unsigned short* __restrict__ Tlo) {
  int i = blockIdx.x * 256 + threadIdx.x;
  const float* src;
  unsigned short *dh, *dl;
  if (i < 65536) { src = S; dh = Shi; dl = Slo; }
  else { src = T; dh = Thi; dl = Tlo; i -= 65536; }
  const float4* p = (const float4*)(src + (size_t)i * 8);
  float4 x = p[0], y = p[1];
  float vals[8] = {x.x, x.y, x.z, x.w, y.x, y.y, y.z, y.w};
  unsigned int h[8], lo[8];
#pragma unroll
  for (int e = 0; e < 8; ++e) {
    unsigned short hr = f2bfr(vals[e]);
    h[e] = hr;
    lo[e] = f2bfr(vals[e] - bflo(hr));
  }
  uint4 hw = make_uint4(h[0] | (h[1] << 16), h[2] | (h[3] << 16),
                        h[4] | (h[5] << 16), h[6] | (h[7] << 16));
  uint4 lw = make_uint4(lo[0] | (lo[1] << 16), lo[2] | (lo[3] << 16),
                        lo[4] | (lo[5] << 16), lo[6] | (lo[7] << 16));
  *(uint4*)(dh + (size_t)i * 8) = hw;
  *(uint4*)(dl + (size_t)i * 8) = lw;
}

// ---------------------------------------------------------------------------
// kernel 2: per-call init. v=1; c=0 (fallback colsum accumulator).
// ---------------------------------------------------------------------------
__global__ __launch_bounds__(256) void init_k(float* __restrict__ c,
                                              float* __restrict__ v_out) {
  int i = blockIdx.x * 256 + threadIdx.x;
  if (i < NTGT) {
    c[i] = 0.f;
    v_out[i] = 1.f;
  }
}

// ---------------------------------------------------------------------------
// kernel 3 (main): MFMA K-build. 64x64 tile/block, 4 waves each 32x32.
// dot = S·T^T via 3 MFMAs per k-step (hi·hi + hi·lo + lo·hi, f32 accum).
// Epilogue: K = exp(-10*sqrt(max(s2+t2-2dot,0))) -> bf16 LDS stage ->
// coalesced Kb write + per-tile row sums (v==1 first u-pass, folded) into
// rowpart[bn][8192] (deterministic, no atomics).
// ---------------------------------------------------------------------------
__global__ __launch_bounds__(256) void kbuild_mfma_k(
    const unsigned short* __restrict__ Shi, const unsigned short* __restrict__ Slo,
    const unsigned short* __restrict__ Thi, const unsigned short* __restrict__ Tlo,
    const float* __restrict__ s2, const float* __restrict__ t2,
    __hip_bfloat16* __restrict__ Kb, float* __restrict__ rowpart) {
  __shared__ unsigned short sAh[64][72], sAl[64][72];
  __shared__ unsigned short sBh[64][72], sBl[64][72];
  __shared__ unsigned short stage[64][72];
  __shared__ float sS2[64], sT2[64];

  const int tid = threadIdx.x;
  const int bm = blockIdx.y * 64, bn = blockIdx.x * 64;

#pragma unroll
  for (int p = 0; p < 2; ++p) {
    int f = tid + 256 * p;
    int row = f >> 3, seg = (f & 7) * 8;
    *(uint4*)&sAh[row][seg] = ((const uint4*)(Shi + (size_t)bm * DIM))[f];
    *(uint4*)&sAl[row][seg] = ((const uint4*)(Slo + (size_t)bm * DIM))[f];
    *(uint4*)&sBh[row][seg] = ((const uint4*)(Thi + (size_t)bn * DIM))[f];
    *(uint4*)&sBl[row][seg] = ((const uint4*)(Tlo + (size_t)bn * DIM))[f];
  }
  if (tid < 64) sS2[tid] = s2[bm + tid];
  else if (tid < 128) sT2[tid - 64] = t2[bn + (tid - 64)];
  __syncthreads();

  const int w = tid >> 6, l = tid & 63;
  const int wr = w >> 1, wc = w & 1;
  const int arow = 32 * wr + (l & 31);
  const int brow = 32 * wc + (l & 31);
  const int kh = 8 * (l >> 5);

  f32x16 acc;
#pragma unroll
  for (int i = 0; i < 16; ++i) acc[i] = 0.f;

#pragma unroll
  for (int ks = 0; ks < 4; ++ks) {
    int ko = 16 * ks + kh;
    bf16x8 ah = *(const bf16x8*)&sAh[arow][ko];
    bf16x8 al = *(const bf16x8*)&sAl[arow][ko];
    bf16x8 bh = *(const bf16x8*)&sBh[brow][ko];
    bf16x8 bl = *(const bf16x8*)&sBl[brow][ko];
    acc = __builtin_amdgcn_mfma_f32_32x32x16_bf16(ah, bh, acc, 0, 0, 0);
    acc = __builtin_amdgcn_mfma_f32_32x32x16_bf16(ah, bl, acc, 0, 0, 0);
    acc = __builtin_amdgcn_mfma_f32_32x32x16_bf16(al, bh, acc, 0, 0, 0);
  }

  // epilogue -> LDS stage (bf16)
#pragma unroll
  for (int j = 0; j < 16; ++j) {
    int rl = (j & 3) + 8 * (j >> 2) + 4 * (l >> 5);
    int row = 32 * wr + rl, col = 32 * wc + (l & 31);
    float sq = sS2[row] + sT2[col] - 2.f * acc[j];
    float kv = __expf(-10.f * sqrtf(fmaxf(sq, 0.f)));
    stage[row][col] = f2bfr(kv);
  }
  __syncthreads();

  // fold first u-pass: deterministic per-tile row sums -> rowpart[bn][row]
  {
    int row = tid >> 2, q = tid & 3;
    float a = 0.f;
#pragma unroll
    for (int m = 0; m < 16; ++m)
      a += bflo((unsigned int)stage[row][16 * q + m]);
    a += __shfl_down(a, 1, 4);
    a += __shfl_down(a, 2, 4);
    if (q == 0) rowpart[(size_t)blockIdx.x * NSRC + bm + row] = a;
  }

  // Kb write (row-major, uint4)
#pragma unroll
  for (int p = 0; p < 2; ++p) {
    int f = tid + 256 * p;
    int row = f >> 3, seg = (f & 7) * 8;
    *(uint4*)(Kb + (size_t)(bm + row) * NTGT + bn + seg) =
        *(const uint4*)&stage[row][seg];
  }
}

// ---------------------------------------------------------------------------
// kernel 3b: u[i] = sw / (sum_bn rowpart[bn][i] + stab)
// ---------------------------------------------------------------------------
__global__ __launch_bounds__(256) void initu_k(const float* __restrict__ rowpart,
                                               float* __restrict__ u) {
  int i = blockIdx.x * 256 + threadIdx.x;
  float a = 0.f;
#pragma unroll 8
  for (int bn = 0; bn < 128; ++bn) a += rowpart[(size_t)bn * NSRC + i];
  u[i] = (1.0f / NSRC) / (a + 1e-8f);
}

// ---------------------------------------------------------------------------
// kernel 4: u-pass: y[r] = (1/8192) / (sum_j Kb[r][j]*x[j] + 1e-8).
// One wave per row, 2048 blocks (32 waves/CU).
// ---------------------------------------------------------------------------
__global__ __launch_bounds__(256) void rowsum_k(const unsigned short* __restrict__ P,
                                                const float* __restrict__ x,
                                                float* __restrict__ y) {
  int row = blockIdx.x * 4 + (threadIdx.x >> 6);
  int lane = threadIdx.x & 63;
  const uint4* r4 = (const uint4*)(P + (size_t)row * NTGT);
  const float4* x4 = (const float4*)x;
  float a = 0.f;
#pragma unroll 4
  for (int s = lane; s < NTGT / 8; s += 64) {
    uint4 q = r4[s];
    float4 xa = x4[2 * s], xb = x4[2 * s + 1];
    a += bflo(q.x) * xa.x + bfhi(q.x) * xa.y
       + bflo(q.y) * xa.z + bfhi(q.y) * xa.w
       + bflo(q.z) * xb.x + bfhi(q.z) * xb.y
       + bflo(q.w) * xb.z + bfhi(q.w) * xb.w;
  }
  a = wave_reduce_sum(a);
  if (lane == 0) y[row] = (1.0f / 8192.0f) / (a + 1e-8f);
}

// ---------------------------------------------------------------------------
// kernel 5: v-pass stage 1: column partials over a 16-row slab.
// Block ic (0..511): c_part[ic][j] = sum_{r<16} Kb[16ic+r][j] * u[16ic+r].
// Thread owns 32 cols (j = 8t+2048s+e). Register accumulators, no atomics.
// ---------------------------------------------------------------------------
__global__ __launch_bounds__(256) void colsum_part_k(
    const unsigned short* __restrict__ Kb,
    const float* __restrict__ u,
    float* __restrict__ c_part) {
  const int ic = blockIdx.x;
  const int t = threadIdx.x;
  const uint4* kp = (const uint4*)(Kb + (size_t)ic * 16 * NTGT);

  float acc[32];
#pragma unroll
  for (int k = 0; k < 32; ++k) acc[k] = 0.f;

#pragma unroll 4
  for (int r = 0; r < 16; ++r) {
    float ui = u[16 * ic + r];
    uint4 q0 = kp[r * 1024 + 0 * 256 + t];
    uint4 q1 = kp[r * 1024 + 1 * 256 + t];
    uint4 q2 = kp[r * 1024 + 2 * 256 + t];
    uint4 q3 = kp[r * 1024 + 3 * 256 + t];
    acc[0]  += bflo(q0.x) * ui; acc[1]  += bfhi(q0.x) * ui;
    acc[2]  += bflo(q0.y) * ui; acc[3]  += bfhi(q0.y) * ui;
    acc[4]  += bflo(q0.z) * ui; acc[5]  += bfhi(q0.z) * ui;
    acc[6]  += bflo(q0.w) * ui; acc[7]  += bfhi(q0.w) * ui;
    acc[8]  += bflo(q1.x) * ui; acc[9]  += bfhi(q1.x) * ui;
    acc[10] += bflo(q1.y) * ui; acc[11] += bfhi(q1.y) * ui;
    acc[12] += bflo(q1.z) * ui; acc[13] += bfhi(q1.z) * ui;
    acc[14] += bflo(q1.w) * ui; acc[15] += bfhi(q1.w) * ui;
    acc[16] += bflo(q2.x) * ui; acc[17] += bfhi(q2.x) * ui;
    acc[18] += bflo(q2.y) * ui; acc[19] += bfhi(q2.y) * ui;
    acc[20] += bflo(q2.z) * ui; acc[21] += bfhi(q2.z) * ui;
    acc[22] += bflo(q2.w) * ui; acc[23] += bfhi(q2.w) * ui;
    acc[24] += bflo(q3.x) * ui; acc[25] += bfhi(q3.x) * ui;
    acc[26] += bflo(q3.y) * ui; acc[27] += bfhi(q3.y) * ui;
    acc[28] += bflo(q3.z) * ui; acc[29] += bfhi(q3.z) * ui;
    acc[30] += bflo(q3.w) * ui; acc[31] += bfhi(q3.w) * ui;
  }

  float* dst = c_part + (size_t)ic * NTGT + 8 * t;
#pragma unroll
  for (int s = 0; s < 4; ++s) {
    *(float4*)(dst + 2048 * s)     = make_float4(acc[8 * s + 0], acc[8 * s + 1],
                                                 acc[8 * s + 2], acc[8 * s + 3]);
    *(float4*)(dst + 2048 * s + 4) = make_float4(acc[8 * s + 4], acc[8 * s + 5],
                                                 acc[8 * s + 6], acc[8 * s + 7]);
  }
}

// ---------------------------------------------------------------------------
// kernel 6: v-pass stage 2: v[j] = tw / (sum_ic c_part[ic][j] + stab)
// ---------------------------------------------------------------------------
__global__ __launch_bounds__(256) void csum1v_k(const float* __restrict__ c_part,
                                                float* __restrict__ v_out) {
  int j = blockIdx.x * 256 + threadIdx.x;
  float a = 0.f;
#pragma unroll 8
  for (int ic = 0; ic < 512; ++ic) a += c_part[(size_t)ic * NTGT + j];
  v_out[j] = (1.0f / NTGT) / (a + 1e-8f);
}

// ---------------------------------------------------------------------------
// kernel C: coupling C = u*Kb*v (f32), dist partials via cost = -0.1*ln(Kb).
// ---------------------------------------------------------------------------
__global__ __launch_bounds__(256) void coupling_bf16_k(
    const unsigned short* __restrict__ Kb,
    const float* __restrict__ u,
    const float* __restrict__ v,
    float* __restrict__ C,
    float* __restrict__ partials) {
  __shared__ float red[4];
  size_t g = (size_t)blockIdx.x * 256 + threadIdx.x;
  size_t base = g * 32;
  int i = (int)(base >> 13);
  int j0 = (int)(base & 8191);
  float ui = u[i];
  const uint4* kp = (const uint4*)(Kb + base);
  const float4* vp = (const float4*)(v + j0);
  float part = 0.f;
#pragma unroll
  for (int s = 0; s < 4; ++s) {
    uint4 q = kp[s];
    float4 va = vp[2 * s], vb = vp[2 * s + 1];
    float k0 = bflo(q.x), k1 = bfhi(q.x), k2 = bflo(q.y), k3 = bfhi(q.y);
    float k4 = bflo(q.z), k5 = bfhi(q.z), k6 = bflo(q.w), k7 = bfhi(q.w);
    float c0 = ui * k0 * va.x, c1 = ui * k1 * va.y;
    float c2 = ui * k2 * va.z, c3 = ui * k3 * va.w;
    float c4 = ui * k4 * vb.x, c5 = ui * k5 * vb.y;
    float c6 = ui * k6 * vb.z, c7 = ui * k7 * vb.w;
    part += c0 * __logf(fmaxf(k0, 1e-37f)) + c1 * __logf(fmaxf(k1, 1e-37f)) +
            c2 * __logf(fmaxf(k2, 1e-37f)) + c3 * __logf(fmaxf(k3, 1e-37f)) +
            c4 * __logf(fmaxf(k4, 1e-37f)) + c5 * __logf(fmaxf(k5, 1e-37f)) +
            c6 * __logf(fmaxf(k6, 1e-37f)) + c7 * __logf(fmaxf(k7, 1e-37f));
    float* cw = C + base + 8 * s;
    *(float4*)cw       = make_float4(c0, c1, c2, c3);
    *(float4*)(cw + 4) = make_float4(c4, c5, c6, c7);
  }
  part = wave_reduce_sum(part);
  int wid = threadIdx.x >> 6, lane = threadIdx.x & 63;
  if (lane == 0) red[wid] = part;
  __syncthreads();
  if (threadIdx.x == 0)
    partials[blockIdx.x] = red[0] + red[1] + red[2] + red[3];
}

// ---------------------------------------------------------------------------
// fallback kernels (f32 path; only if ws too small for main path)
// ---------------------------------------------------------------------------
#define BM 64
#define BN 128
__global__ __launch_bounds__(256) void kbuild_k(const float* __restrict__ S,
                                                const float* __restrict__ T,
                                                const float* __restrict__ s2,
                                                const float* __restrict__ t2,
                                                float* __restrict__ Kf) {
  __shared__ float sT[BM][68];
  __shared__ float tT[BN][68];
  const int bn = blockIdx.x * BN;
  const int bm = blockIdx.y * BM;
  const int tid = threadIdx.x;
  {
    const float4* sg = (const float4*)(S + (size_t)bm * DIM);
#pragma unroll
    for (int k = 0; k < 4; ++k) {
      int f = tid + 256 * k;
      int row = f >> 4, c4 = f & 15;
      *(float4*)&sT[row][c4 * 4] = sg[f];
    }
    const float4* tg = (const float4*)(T + (size_t)bn * DIM);
#pragma unroll
    for (int k = 0; k < 8; ++k) {
      int f = tid + 256 * k;
      int row = f >> 4, c4 = f & 15;
      *(float4*)&tT[row][c4 * 4] = tg[f];
    }
  }
  __syncthreads();
  const int tx = tid & 15;
  const int ty = tid >> 4;
  float acc[4][8];
#pragma unroll
  for (int a = 0; a < 4; ++a)
#pragma unroll
    for (int b = 0; b < 8; ++b) acc[a][b] = 0.f;
  for (int k = 0; k < DIM; k += 4) {
    float4 sr[4], trg[8];
#pragma unroll
    for (int a = 0; a < 4; ++a) sr[a] = *(float4*)&sT[ty + 16 * a][k];
#pragma unroll
    for (int b = 0; b < 8; ++b) trg[b] = *(float4*)&tT[tx + 16 * b][k];
#pragma unroll
    for (int a = 0; a < 4; ++a)
#pragma unroll
      for (int b = 0; b < 8; ++b) {
        acc[a][b] += sr[a].x * trg[b].x;
        acc[a][b] += sr[a].y * trg[b].y;
        acc[a][b] += sr[a].z * trg[b].z;
        acc[a][b] += sr[a].w * trg[b].w;
      }
  }
#pragma unroll
  for (int a = 0; a < 4; ++a) {
    int gi = bm + ty + 16 * a;
    float s2v = s2[gi];
#pragma unroll
    for (int b = 0; b < 8; ++b) {
      int gj = bn + tx + 16 * b;
      float sq = s2v + t2[gj] - 2.f * acc[a][b];
      float cost = sqrtf(fmaxf(sq, 0.f));
      Kf[(size_t)gi * NTGT + gj] = __expf(-10.f * cost);
    }
  }
}

__global__ __launch_bounds__(256) void rowsum_f32_k(const float* __restrict__ K,
                                                    const float* __restrict__ v,
                                                    float* __restrict__ u_out) {
  int row = (blockIdx.x * 256 + threadIdx.x) >> 6;
  int lane = threadIdx.x & 63;
  const float4* r4 = (const float4*)(K + (size_t)row * NTGT);
  const float4* v4 = (const float4*)v;
  float a = 0.f;
#pragma unroll 4
  for (int j = lane; j < NTGT / 4; j += 64) {
    float4 k4 = r4[j];
    float4 vv = v4[j];
    a += k4.x * vv.x + k4.y * vv.y + k4.z * vv.z + k4.w * vv.w;
  }
  a = wave_reduce_sum(a);
  if (lane == 0) u_out[row] = (1.0f / NSRC) / (a + 1e-8f);
}

__global__ __launch_bounds__(256) void colsum_f32_k(const float* __restrict__ K,
                                                    const float* __restrict__ u,
                                                    float* __restrict__ c) {
  int j = blockIdx.x * 1024 + threadIdx.x * 4;
  int i0 = blockIdx.y * 64;
  float a0 = 0.f, a1 = 0.f, a2 = 0.f, a3 = 0.f;
#pragma unroll 8
  for (int i = i0; i < i0 + 64; ++i) {
    float ui = u[i];
    float4 k4 = *(const float4*)(K + (size_t)i * NTGT + j);
    a0 += k4.x * ui; a1 += k4.y * ui; a2 += k4.z * ui; a3 += k4.w * ui;
  }
  atomicAdd(&c[j + 0], a0);
  atomicAdd(&c[j + 1], a1);
  atomicAdd(&c[j + 2], a2);
  atomicAdd(&c[j + 3], a3);
}

__global__ __launch_bounds__(256) void finishv_k(float* __restrict__ c,
                                                 float* __restrict__ v_out) {
  int j = blockIdx.x * 256 + threadIdx.x;
  v_out[j] = (1.0f / NTGT) / (c[j] + 1e-8f);
  c[j] = 0.f;
}

__global__ __launch_bounds__(256) void coupling_f32_k(float* __restrict__ K,
                                                      const float* __restrict__ u,
                                                      const float* __restrict__ v,
                                                      float* __restrict__ partials) {
  __shared__ float red[4];
  size_t t0 = (size_t)blockIdx.x * 2048 + threadIdx.x;
  float part = 0.f;
#pragma unroll
  for (int s = 0; s < 8; ++s) {
    size_t f4 = t0 + (size_t)s * 256;
    size_t base = f4 * 4;
    int i = (int)(base >> 13);
    int j = (int)(base & 8191);
    float4 k4 = *(float4*)(K + base);
    float ui = u[i];
    float4 vv = *(const float4*)(v + j);
    float c0 = ui * k4.x * vv.x;
    float c1 = ui * k4.y * vv.y;
    float c2 = ui * k4.z * vv.z;
    float c3 = ui * k4.w * vv.w;
    part += c0 * __logf(k4.x) + c1 * __logf(k4.y) +
            c2 * __logf(k4.z) + c3 * __logf(k4.w);
    *(float4*)(K + base) = make_float4(c0, c1, c2, c3);
  }
  part = wave_reduce_sum(part);
  int wid = threadIdx.x >> 6, lane = threadIdx.x & 63;
  if (lane == 0) red[wid] = part;
  __syncthreads();
  if (threadIdx.x == 0)
    partials[blockIdx.x] = red[0] + red[1] + red[2] + red[3];
}

// ---------------------------------------------------------------------------
// kernel 8: dist = -eps * sum(partials) / (ns*nt)
// ---------------------------------------------------------------------------
__global__ __launch_bounds__(256) void finalize_k(const float* __restrict__ partials,
                                                  float* __restrict__ out) {
  __shared__ float red[4];
  float a = 0.f;
  for (int i = threadIdx.x; i < 8192; i += 256) a += partials[i];
  a = wave_reduce_sum(a);
  int wid = threadIdx.x >> 6, lane = threadIdx.x & 63;
  if (lane == 0) red[wid] = a;
  __syncthreads();
  if (threadIdx.x == 0)
    out[0] = (red[0] + red[1] + red[2] + red[3]) *
             (-0.1f / ((float)NSRC * (float)NTGT));
}

// ---------------------------------------------------------------------------
extern "C" void kernel_launch(void* const* d_in, const int* in_sizes, int n_in,
                              void* d_out, int out_size, void* d_ws, size_t ws_size,
                              hipStream_t stream) {
  const float* S = (const float*)d_in[0];
  const float* T = (const float*)d_in[1];
  float* out = (float*)d_out;

  // output layout: [dist(1)][coupling(64M)][u(8192)][v(8192)]
  float* C  = out + 1;
  float* u  = out + 1 + (size_t)NSRC * NTGT;
  float* vv = u + NSRC;

  // ws byte layout (total = 512K + 128M + 16M = 144.5 MB, proven round 3):
  //   s2 @0(32K) t2 @32K partials @64K c @96K(fallback)
  //   Kb     @512K        (128 MB)   <- the ONLY large iteration buffer
  //   c_part @512K+128M   (16 MB)
  //     overlapped (dead before first colsum):
  //       Shi/Slo/Thi/Tlo @c_part+{0,1,2,3}M (1 MB each)
  //       rowpart         @c_part+4M (4 MB)
  char* wsb = (char*)d_ws;
  float* s2       = (float*)(wsb);
  float* t2       = (float*)(wsb + (32 << 10));
  float* partials = (float*)(wsb + (64 << 10));
  float* c        = (float*)(wsb + (96 << 10));
  const size_t KB_OFF = 512 << 10;
  const size_t KB_BYTES = (size_t)NSRC * NTGT * 2;  // 128 MB
  const size_t CP_OFF = KB_OFF + KB_BYTES;
  const size_t CP_BYTES = (size_t)512 * NTGT * 4;   // 16 MB
  __hip_bfloat16* Kb = (__hip_bfloat16*)(wsb + KB_OFF);
  float* c_part = (float*)(wsb + CP_OFF);
  unsigned short* Shi = (unsigned short*)(wsb + CP_OFF);
  unsigned short* Slo = (unsigned short*)(wsb + CP_OFF + (1 << 20));
  unsigned short* Thi = (unsigned short*)(wsb + CP_OFF + (2 << 20));
  unsigned short* Tlo = (unsigned short*)(wsb + CP_OFF + (3 << 20));
  float* rowpart = (float*)(wsb + CP_OFF + (4 << 20));

  bool full = ws_size >= CP_OFF + CP_BYTES;

  norms_k<<<(NSRC + NTGT + 255) / 256, 256, 0, stream>>>(S, T, s2, t2);
  init_k<<<NTGT / 256, 256, 0, stream>>>(c, vv);

  if (full) {
    prep_k<<<512, 256, 0, stream>>>(S, T, Shi, Slo, Thi, Tlo);
    kbuild_mfma_k<<<dim3(128, 128), 256, 0, stream>>>(
        Shi, Slo, Thi, Tlo, s2, t2, Kb, rowpart);
    initu_k<<<NSRC / 256, 256, 0, stream>>>(rowpart, u);
    for (int it = 0; it < 10; ++it) {
      if (it > 0)
        rowsum_k<<<NSRC / 4, 256, 0, stream>>>((const unsigned short*)Kb, vv, u);
      colsum_part_k<<<512, 256, 0, stream>>>((const unsigned short*)Kb, u, c_part);
      csum1v_k<<<NTGT / 256, 256, 0, stream>>>(c_part, vv);
    }
    coupling_bf16_k<<<8192, 256, 0, stream>>>(
        (const unsigned short*)Kb, u, vv, C, partials);
  } else {
    kbuild_k<<<dim3(NTGT / BN, NSRC / BM), 256, 0, stream>>>(S, T, s2, t2, C);
    for (int it = 0; it < 10; ++it) {
      rowsum_f32_k<<<NSRC * 64 / 256, 256, 0, stream>>>(C, vv, u);
      colsum_f32_k<<<dim3(8, 128), 256, 0, stream>>>(C, u, c);
      finishv_k<<<NTGT / 256, 256, 0, stream>>>(c, vv);
    }
    coupling_f32_k<<<8192, 256, 0, stream>>>(C, u, vv, partials);
  }
  finalize_k<<<1, 256, 0, stream>>>(partials, out);
}

// Round 9
// 722.189 us; speedup vs baseline: 1.1917x; 1.1917x over previous
//
#include <hip/hip_runtime.h>
#include <hip/hip_bf16.h>
#include <math.h>

#define NSRC 8192
#define NTGT 8192
#define DIM 64

typedef short bf16x8 __attribute__((ext_vector_type(8)));
typedef float f32x16 __attribute__((ext_vector_type(16)));

// ---------------------------------------------------------------------------
// helpers
// ---------------------------------------------------------------------------
__device__ __forceinline__ float wave_reduce_sum(float x) {
#pragma unroll
  for (int off = 32; off > 0; off >>= 1) x += __shfl_down(x, off, 64);
  return x;
}

__device__ __forceinline__ float bflo(unsigned int u) {  // low bf16 of a u32
  return __uint_as_float(u << 16);
}
__device__ __forceinline__ float bfhi(unsigned int u) {  // high bf16 of a u32
  return __uint_as_float(u & 0xFFFF0000u);
}
__device__ __forceinline__ unsigned short f2bfr(float x) {
  __hip_bfloat16 b = __float2bfloat16(x);
  return __hip_bfloat16_raw(b).x;
}

// ---------------------------------------------------------------------------
// kernel 1: squared norms of source rows and target rows (f32 inputs)
// ---------------------------------------------------------------------------
__global__ __launch_bounds__(256) void norms_k(const float* __restrict__ S,
                                               const float* __restrict__ T,
                                               float* __restrict__ s2,
                                               float* __restrict__ t2) {
  int i = blockIdx.x * 256 + threadIdx.x;
  if (i >= NSRC + NTGT) return;
  const float* base = (i < NSRC) ? (S + (size_t)i * DIM)
                                 : (T + (size_t)(i - NSRC) * DIM);
  const float4* p = (const float4*)base;
  float a = 0.f;
#pragma unroll
  for (int k = 0; k < DIM / 4; ++k) {
    float4 v = p[k];
    a += v.x * v.x + v.y * v.y + v.z * v.z + v.w * v.w;
  }
  if (i < NSRC) s2[i] = a;
  else          t2[i - NSRC] = a;
}

// ---------------------------------------------------------------------------
// kernel 1b: split features into bf16 hi + bf16 lo (lo = x - float(hi)).
// ---------------------------------------------------------------------------
__global__ __launch_bounds__(256) void prep_k(const float* __restrict__ S,
                                              const float* __restrict__ T,
                                              unsigned short* __restrict__ Shi,
                                              unsigned short* __restrict__ Slo,
                                              unsigned short* __restrict__ Thi,
                                              unsigned short* __restrict__ Tlo) {
  int i = blockIdx.x * 256 + threadIdx.x;
  const float* src;
  unsigned short *dh, *dl;
  if (i < 65536) { src = S; dh = Shi; dl = Slo; }
  else { src = T; dh = Thi; dl = Tlo; i -= 65536; }
  const float4* p = (const float4*)(src + (size_t)i * 8);
  float4 x = p[0], y = p[1];
  float vals[8] = {x.x, x.y, x.z, x.w, y.x, y.y, y.z, y.w};
  unsigned int h[8], lo[8];
#pragma unroll
  for (int e = 0; e < 8; ++e) {
    unsigned short hr = f2bfr(vals[e]);
    h[e] = hr;
    lo[e] = f2bfr(vals[e] - bflo(hr));
  }
  uint4 hw = make_uint4(h[0] | (h[1] << 16), h[2] | (h[3] << 16),
                        h[4] | (h[5] << 16), h[6] | (h[7] << 16));
  uint4 lw = make_uint4(lo[0] | (lo[1] << 16), lo[2] | (lo[3] << 16),
                        lo[4] | (lo[5] << 16), lo[6] | (lo[7] << 16));
  *(uint4*)(dh + (size_t)i * 8) = hw;
  *(uint4*)(dl + (size_t)i * 8) = lw;
}

// ---------------------------------------------------------------------------
// kernel 2: per-call init. v=1; c=0 (fallback colsum accumulator).
// ---------------------------------------------------------------------------
__global__ __launch_bounds__(256) void init_k(float* __restrict__ c,
                                              float* __restrict__ v_out) {
  int i = blockIdx.x * 256 + threadIdx.x;
  if (i < NTGT) {
    c[i] = 0.f;
    v_out[i] = 1.f;
  }
}

// ---------------------------------------------------------------------------
// kernel 3 (main): MFMA K-build. 64x64 tile/block, 4 waves each 32x32.
// dot = S·T^T via 3 MFMAs per k-step (hi·hi + hi·lo + lo·hi, f32 accum).
// Epilogue: K = exp(-10*sqrt(max(s2+t2-2dot,0))) -> bf16 staged in LDS with
// row-bit-swap swizzle PR(r), then coalesced Kb write + transposed KbT write
// + deterministic per-tile row-sum fold (first u-pass, v==1) into
// rowpart[bn][8192]. No atomics.
// ---------------------------------------------------------------------------
#define PR(r) ((((r) >> 3) + (((r)&7) << 3)))

__global__ __launch_bounds__(256) void kbuild_mfma_k(
    const unsigned short* __restrict__ Shi, const unsigned short* __restrict__ Slo,
    const unsigned short* __restrict__ Thi, const unsigned short* __restrict__ Tlo,
    const float* __restrict__ s2, const float* __restrict__ t2,
    __hip_bfloat16* __restrict__ Kb, __hip_bfloat16* __restrict__ KbT,
    float* __restrict__ rowpart) {
  __shared__ unsigned short sAh[64][72], sAl[64][72];
  __shared__ unsigned short sBh[64][72], sBl[64][72];
  __shared__ unsigned short stage[64][72];
  __shared__ float sS2[64], sT2[64];

  const int tid = threadIdx.x;
  const int bm = blockIdx.y * 64, bn = blockIdx.x * 64;

#pragma unroll
  for (int p = 0; p < 2; ++p) {
    int f = tid + 256 * p;
    int row = f >> 3, seg = (f & 7) * 8;
    *(uint4*)&sAh[row][seg] = ((const uint4*)(Shi + (size_t)bm * DIM))[f];
    *(uint4*)&sAl[row][seg] = ((const uint4*)(Slo + (size_t)bm * DIM))[f];
    *(uint4*)&sBh[row][seg] = ((const uint4*)(Thi + (size_t)bn * DIM))[f];
    *(uint4*)&sBl[row][seg] = ((const uint4*)(Tlo + (size_t)bn * DIM))[f];
  }
  if (tid < 64) sS2[tid] = s2[bm + tid];
  else if (tid < 128) sT2[tid - 64] = t2[bn + (tid - 64)];
  __syncthreads();

  const int w = tid >> 6, l = tid & 63;
  const int wr = w >> 1, wc = w & 1;
  const int arow = 32 * wr + (l & 31);
  const int brow = 32 * wc + (l & 31);
  const int kh = 8 * (l >> 5);

  f32x16 acc;
#pragma unroll
  for (int i = 0; i < 16; ++i) acc[i] = 0.f;

#pragma unroll
  for (int ks = 0; ks < 4; ++ks) {
    int ko = 16 * ks + kh;
    bf16x8 ah = *(const bf16x8*)&sAh[arow][ko];
    bf16x8 al = *(const bf16x8*)&sAl[arow][ko];
    bf16x8 bh = *(const bf16x8*)&sBh[brow][ko];
    bf16x8 bl = *(const bf16x8*)&sBl[brow][ko];
    acc = __builtin_amdgcn_mfma_f32_32x32x16_bf16(ah, bh, acc, 0, 0, 0);
    acc = __builtin_amdgcn_mfma_f32_32x32x16_bf16(ah, bl, acc, 0, 0, 0);
    acc = __builtin_amdgcn_mfma_f32_32x32x16_bf16(al, bh, acc, 0, 0, 0);
  }

  // epilogue -> swizzled LDS stage (bf16)
#pragma unroll
  for (int j = 0; j < 16; ++j) {
    int rl = (j & 3) + 8 * (j >> 2) + 4 * (l >> 5);
    int row = 32 * wr + rl, col = 32 * wc + (l & 31);
    float sq = sS2[row] + sT2[col] - 2.f * acc[j];
    float kv = __expf(-10.f * sqrtf(fmaxf(sq, 0.f)));
    stage[PR(row)][col] = f2bfr(kv);
  }
  __syncthreads();

  // fold first u-pass: deterministic per-tile row sums -> rowpart[bn][row]
  {
    int row = tid >> 2, q = tid & 3;
    float a = 0.f;
#pragma unroll
    for (int m = 0; m < 16; ++m)
      a += bflo((unsigned int)stage[PR(row)][16 * q + m]);
    a += __shfl_down(a, 1, 4);
    a += __shfl_down(a, 2, 4);
    if (q == 0) rowpart[(size_t)blockIdx.x * NSRC + bm + row] = a;
  }

  // Kb write (row-major)
#pragma unroll
  for (int p = 0; p < 2; ++p) {
    int f = tid + 256 * p;
    int row = f >> 3, seg = (f & 7) * 8;
    *(uint4*)(Kb + (size_t)(bm + row) * NTGT + bn + seg) =
        *(const uint4*)&stage[PR(row)][seg];
  }
  // KbT write (transposed): thread owns (source col tcol, 8-row group gro)
#pragma unroll
  for (int p = 0; p < 2; ++p) {
    int f = tid + 256 * p;
    int tcol = f >> 3, gro = f & 7;
    unsigned int wds[4];
#pragma unroll
    for (int e = 0; e < 4; ++e) {
      unsigned int a0 = stage[gro + 8 * (2 * e)][tcol];
      unsigned int a1 = stage[gro + 8 * (2 * e + 1)][tcol];
      wds[e] = a0 | (a1 << 16);
    }
    *(uint4*)(KbT + (size_t)(bn + tcol) * NSRC + bm + 8 * gro) =
        make_uint4(wds[0], wds[1], wds[2], wds[3]);
  }
}

// ---------------------------------------------------------------------------
// kernel 3b: u[i] = sw / (sum_bn rowpart[bn][i] + stab)
// ---------------------------------------------------------------------------
__global__ __launch_bounds__(256) void initu_k(const float* __restrict__ rowpart,
                                               float* __restrict__ u) {
  int i = blockIdx.x * 256 + threadIdx.x;
  float a = 0.f;
#pragma unroll 8
  for (int bn = 0; bn < 128; ++bn) a += rowpart[(size_t)bn * NSRC + i];
  u[i] = (1.0f / NSRC) / (a + 1e-8f);
}

// ---------------------------------------------------------------------------
// kernel 4: y[r] = (1/8192) / (sum_j P[r][j]*x[j] + 1e-8). One wave/row,
// 2048 blocks (32 waves/CU). Used for both Kb (->u) and KbT (->v).
// ---------------------------------------------------------------------------
__global__ __launch_bounds__(256) void rowsum_k(const unsigned short* __restrict__ P,
                                                const float* __restrict__ x,
                                                float* __restrict__ y) {
  int row = blockIdx.x * 4 + (threadIdx.x >> 6);
  int lane = threadIdx.x & 63;
  const uint4* r4 = (const uint4*)(P + (size_t)row * NTGT);
  const float4* x4 = (const float4*)x;
  float a = 0.f;
#pragma unroll 8
  for (int s = lane; s < NTGT / 8; s += 64) {
    uint4 q = r4[s];
    float4 xa = x4[2 * s], xb = x4[2 * s + 1];
    a += bflo(q.x) * xa.x + bfhi(q.x) * xa.y
       + bflo(q.y) * xa.z + bfhi(q.y) * xa.w
       + bflo(q.z) * xb.x + bfhi(q.z) * xb.y
       + bflo(q.w) * xb.z + bfhi(q.w) * xb.w;
  }
  a = wave_reduce_sum(a);
  if (lane == 0) y[row] = (1.0f / 8192.0f) / (a + 1e-8f);
}

// ---------------------------------------------------------------------------
// kernel C: coupling by RECOMPUTATION (no Kb read). Same MFMA tile as kbuild:
// recompute dot -> cost (exact f32) -> K, then C = u*K*v (write once) and
// partials += C*cost. Deterministic per-block partials.
// ---------------------------------------------------------------------------
__global__ __launch_bounds__(256) void coupling_rc_k(
    const unsigned short* __restrict__ Shi, const unsigned short* __restrict__ Slo,
    const unsigned short* __restrict__ Thi, const unsigned short* __restrict__ Tlo,
    const float* __restrict__ s2, const float* __restrict__ t2,
    const float* __restrict__ u, const float* __restrict__ v,
    float* __restrict__ C, float* __restrict__ partials) {
  __shared__ unsigned short sAh[64][72], sAl[64][72];
  __shared__ unsigned short sBh[64][72], sBl[64][72];
  __shared__ float sS2[64], sT2[64], sU[64], sV[64];
  __shared__ float red[4];

  const int tid = threadIdx.x;
  const int bm = blockIdx.y * 64, bn = blockIdx.x * 64;

#pragma unroll
  for (int p = 0; p < 2; ++p) {
    int f = tid + 256 * p;
    int row = f >> 3, seg = (f & 7) * 8;
    *(uint4*)&sAh[row][seg] = ((const uint4*)(Shi + (size_t)bm * DIM))[f];
    *(uint4*)&sAl[row][seg] = ((const uint4*)(Slo + (size_t)bm * DIM))[f];
    *(uint4*)&sBh[row][seg] = ((const uint4*)(Thi + (size_t)bn * DIM))[f];
    *(uint4*)&sBl[row][seg] = ((const uint4*)(Tlo + (size_t)bn * DIM))[f];
  }
  if (tid < 64)       sS2[tid] = s2[bm + tid];
  else if (tid < 128) sT2[tid - 64] = t2[bn + (tid - 64)];
  else if (tid < 192) sU[tid - 128] = u[bm + (tid - 128)];
  else                sV[tid - 192] = v[bn + (tid - 192)];
  __syncthreads();

  const int w = tid >> 6, l = tid & 63;
  const int wr = w >> 1, wc = w & 1;
  const int arow = 32 * wr + (l & 31);
  const int brow = 32 * wc + (l & 31);
  const int kh = 8 * (l >> 5);

  f32x16 acc;
#pragma unroll
  for (int i = 0; i < 16; ++i) acc[i] = 0.f;

#pragma unroll
  for (int ks = 0; ks < 4; ++ks) {
    int ko = 16 * ks + kh;
    bf16x8 ah = *(const bf16x8*)&sAh[arow][ko];
    bf16x8 al = *(const bf16x8*)&sAl[arow][ko];
    bf16x8 bh = *(const bf16x8*)&sBh[brow][ko];
    bf16x8 bl = *(const bf16x8*)&sBl[brow][ko];
    acc = __builtin_amdgcn_mfma_f32_32x32x16_bf16(ah, bh, acc, 0, 0, 0);
    acc = __builtin_amdgcn_mfma_f32_32x32x16_bf16(ah, bl, acc, 0, 0, 0);
    acc = __builtin_amdgcn_mfma_f32_32x32x16_bf16(al, bh, acc, 0, 0, 0);
  }

  float part = 0.f;
#pragma unroll
  for (int j = 0; j < 16; ++j) {
    int rl = (j & 3) + 8 * (j >> 2) + 4 * (l >> 5);
    int row = 32 * wr + rl, col = 32 * wc + (l & 31);
    float sq = sS2[row] + sT2[col] - 2.f * acc[j];
    float cost = sqrtf(fmaxf(sq, 0.f));
    float kv = __expf(-10.f * cost);
    float cpl = sU[row] * kv * sV[col];
    C[(size_t)(bm + row) * NTGT + bn + col] = cpl;
    part += cpl * cost;
  }
  part = wave_reduce_sum(part);
  if (l == 0) red[w] = part;
  __syncthreads();
  if (tid == 0)
    partials[blockIdx.y * 128 + blockIdx.x] = red[0] + red[1] + red[2] + red[3];
}

// ---------------------------------------------------------------------------
// fallback kernels (f32 path; only if ws too small for main path)
// ---------------------------------------------------------------------------
#define BM 64
#define BN 128
__global__ __launch_bounds__(256) void kbuild_k(const float* __restrict__ S,
                                                const float* __restrict__ T,
                                                const float* __restrict__ s2,
                                                const float* __restrict__ t2,
                                                float* __restrict__ Kf) {
  __shared__ float sT[BM][68];
  __shared__ float tT[BN][68];
  const int bn = blockIdx.x * BN;
  const int bm = blockIdx.y * BM;
  const int tid = threadIdx.x;
  {
    const float4* sg = (const float4*)(S + (size_t)bm * DIM);
#pragma unroll
    for (int k = 0; k < 4; ++k) {
      int f = tid + 256 * k;
      int row = f >> 4, c4 = f & 15;
      *(float4*)&sT[row][c4 * 4] = sg[f];
    }
    const float4* tg = (const float4*)(T + (size_t)bn * DIM);
#pragma unroll
    for (int k = 0; k < 8; ++k) {
      int f = tid + 256 * k;
      int row = f >> 4, c4 = f & 15;
      *(float4*)&tT[row][c4 * 4] = tg[f];
    }
  }
  __syncthreads();
  const int tx = tid & 15;
  const int ty = tid >> 4;
  float acc[4][8];
#pragma unroll
  for (int a = 0; a < 4; ++a)
#pragma unroll
    for (int b = 0; b < 8; ++b) acc[a][b] = 0.f;
  for (int k = 0; k < DIM; k += 4) {
    float4 sr[4], trg[8];
#pragma unroll
    for (int a = 0; a < 4; ++a) sr[a] = *(float4*)&sT[ty + 16 * a][k];
#pragma unroll
    for (int b = 0; b < 8; ++b) trg[b] = *(float4*)&tT[tx + 16 * b][k];
#pragma unroll
    for (int a = 0; a < 4; ++a)
#pragma unroll
      for (int b = 0; b < 8; ++b) {
        acc[a][b] += sr[a].x * trg[b].x;
        acc[a][b] += sr[a].y * trg[b].y;
        acc[a][b] += sr[a].z * trg[b].z;
        acc[a][b] += sr[a].w * trg[b].w;
      }
  }
#pragma unroll
  for (int a = 0; a < 4; ++a) {
    int gi = bm + ty + 16 * a;
    float s2v = s2[gi];
#pragma unroll
    for (int b = 0; b < 8; ++b) {
      int gj = bn + tx + 16 * b;
      float sq = s2v + t2[gj] - 2.f * acc[a][b];
      float cost = sqrtf(fmaxf(sq, 0.f));
      Kf[(size_t)gi * NTGT + gj] = __expf(-10.f * cost);
    }
  }
}

__global__ __launch_bounds__(256) void rowsum_f32_k(const float* __restrict__ K,
                                                    const float* __restrict__ v,
                                                    float* __restrict__ u_out) {
  int row = (blockIdx.x * 256 + threadIdx.x) >> 6;
  int lane = threadIdx.x & 63;
  const float4* r4 = (const float4*)(K + (size_t)row * NTGT);
  const float4* v4 = (const float4*)v;
  float a = 0.f;
#pragma unroll 4
  for (int j = lane; j < NTGT / 4; j += 64) {
    float4 k4 = r4[j];
    float4 vv = v4[j];
    a += k4.x * vv.x + k4.y * vv.y + k4.z * vv.z + k4.w * vv.w;
  }
  a = wave_reduce_sum(a);
  if (lane == 0) u_out[row] = (1.0f / NSRC) / (a + 1e-8f);
}

__global__ __launch_bounds__(256) void colsum_f32_k(const float* __restrict__ K,
                                                    const float* __restrict__ u,
                                                    float* __restrict__ c) {
  int j = blockIdx.x * 1024 + threadIdx.x * 4;
  int i0 = blockIdx.y * 64;
  float a0 = 0.f, a1 = 0.f, a2 = 0.f, a3 = 0.f;
#pragma unroll 8
  for (int i = i0; i < i0 + 64; ++i) {
    float ui = u[i];
    float4 k4 = *(const float4*)(K + (size_t)i * NTGT + j);
    a0 += k4.x * ui; a1 += k4.y * ui; a2 += k4.z * ui; a3 += k4.w * ui;
  }
  atomicAdd(&c[j + 0], a0);
  atomicAdd(&c[j + 1], a1);
  atomicAdd(&c[j + 2], a2);
  atomicAdd(&c[j + 3], a3);
}

__global__ __launch_bounds__(256) void finishv_k(float* __restrict__ c,
                                                 float* __restrict__ v_out) {
  int j = blockIdx.x * 256 + threadIdx.x;
  v_out[j] = (1.0f / NTGT) / (c[j] + 1e-8f);
  c[j] = 0.f;
}

__global__ __launch_bounds__(256) void coupling_f32_k(float* __restrict__ K,
                                                      const float* __restrict__ u,
                                                      const float* __restrict__ v,
                                                      float* __restrict__ partials) {
  __shared__ float red[4];
  size_t t0 = (size_t)blockIdx.x * 2048 + threadIdx.x;
  float part = 0.f;
#pragma unroll
  for (int s = 0; s < 8; ++s) {
    size_t f4 = t0 + (size_t)s * 256;
    size_t base = f4 * 4;
    int i = (int)(base >> 13);
    int j = (int)(base & 8191);
    float4 k4 = *(float4*)(K + base);
    float ui = u[i];
    float4 vv = *(const float4*)(v + j);
    float c0 = ui * k4.x * vv.x;
    float c1 = ui * k4.y * vv.y;
    float c2 = ui * k4.z * vv.z;
    float c3 = ui * k4.w * vv.w;
    part += c0 * __logf(k4.x) + c1 * __logf(k4.y) +
            c2 * __logf(k4.z) + c3 * __logf(k4.w);
    *(float4*)(K + base) = make_float4(c0, c1, c2, c3);
  }
  part = wave_reduce_sum(part);
  int wid = threadIdx.x >> 6, lane = threadIdx.x & 63;
  if (lane == 0) red[wid] = part;
  __syncthreads();
  if (threadIdx.x == 0)
    partials[blockIdx.x] = red[0] + red[1] + red[2] + red[3];
}

// ---------------------------------------------------------------------------
// kernel 8: dist = -eps * sum(partials)/(ns*nt)   (fallback: log-based, so
// scale -0.1; main path passes pre-scaled positive partials, scale +1)
// npart = number of partial entries.
// ---------------------------------------------------------------------------
__global__ __launch_bounds__(256) void finalize_k(const float* __restrict__ partials,
                                                  float* __restrict__ out,
                                                  int npart, float scale) {
  __shared__ float red[4];
  float a = 0.f;
  for (int i = threadIdx.x; i < npart; i += 256) a += partials[i];
  a = wave_reduce_sum(a);
  int wid = threadIdx.x >> 6, lane = threadIdx.x & 63;
  if (lane == 0) red[wid] = a;
  __syncthreads();
  if (threadIdx.x == 0)
    out[0] = (red[0] + red[1] + red[2] + red[3]) *
             (scale / ((float)NSRC * (float)NTGT));
}

// ---------------------------------------------------------------------------
extern "C" void kernel_launch(void* const* d_in, const int* in_sizes, int n_in,
                              void* d_out, int out_size, void* d_ws, size_t ws_size,
                              hipStream_t stream) {
  const float* S = (const float*)d_in[0];
  const float* T = (const float*)d_in[1];
  float* out = (float*)d_out;

  // output layout: [dist(1)][coupling(64M)][u(8192)][v(8192)]
  float* C  = out + 1;
  float* u  = out + 1 + (size_t)NSRC * NTGT;
  float* vv = u + NSRC;

  // KbT lives in the C region during the iterations (dead until coupling;
  // coupling_rc overwrites every element). +4B base: dword-aligned, proven.
  __hip_bfloat16* KbT = (__hip_bfloat16*)C;

  // ws byte layout (total = 16M + 128M = 144 MB; 144.5 proven round 3):
  //   s2 @0(32K) t2 @32K c @64K(32K, fallback) partials @128K(64K: 16384 f32)
  //   rowpart @1M (4 MB)
  //   Shi @6M Slo @7M Thi @8M Tlo @9M (1 MB each)
  //   Kb @16M (128 MB)
  char* wsb = (char*)d_ws;
  float* s2       = (float*)(wsb);
  float* t2       = (float*)(wsb + (32 << 10));
  float* c        = (float*)(wsb + (64 << 10));
  float* partials = (float*)(wsb + (128 << 10));
  float* rowpart  = (float*)(wsb + (1 << 20));
  unsigned short* Shi = (unsigned short*)(wsb + ((size_t)6 << 20));
  unsigned short* Slo = (unsigned short*)(wsb + ((size_t)7 << 20));
  unsigned short* Thi = (unsigned short*)(wsb + ((size_t)8 << 20));
  unsigned short* Tlo = (unsigned short*)(wsb + ((size_t)9 << 20));
  const size_t KB_OFF = (size_t)16 << 20;
  const size_t KB_BYTES = (size_t)NSRC * NTGT * 2;  // 128 MB
  __hip_bfloat16* Kb = (__hip_bfloat16*)(wsb + KB_OFF);

  bool full = ws_size >= KB_OFF + KB_BYTES;

  norms_k<<<(NSRC + NTGT + 255) / 256, 256, 0, stream>>>(S, T, s2, t2);

  if (full) {
    prep_k<<<512, 256, 0, stream>>>(S, T, Shi, Slo, Thi, Tlo);
    kbuild_mfma_k<<<dim3(128, 128), 256, 0, stream>>>(
        Shi, Slo, Thi, Tlo, s2, t2, Kb, KbT, rowpart);
    initu_k<<<NSRC / 256, 256, 0, stream>>>(rowpart, u);
    for (int it = 0; it < 10; ++it) {
      if (it > 0)
        rowsum_k<<<NSRC / 4, 256, 0, stream>>>((const unsigned short*)Kb, vv, u);
      rowsum_k<<<NTGT / 4, 256, 0, stream>>>((const unsigned short*)KbT, u, vv);
    }
    coupling_rc_k<<<dim3(128, 128), 256, 0, stream>>>(
        Shi, Slo, Thi, Tlo, s2, t2, u, vv, C, partials);
    finalize_k<<<1, 256, 0, stream>>>(partials, out, 16384, 1.0f);
  } else {
    init_k<<<NTGT / 256, 256, 0, stream>>>(c, vv);
    kbuild_k<<<dim3(NTGT / BN, NSRC / BM), 256, 0, stream>>>(S, T, s2, t2, C);
    for (int it = 0; it < 10; ++it) {
      rowsum_f32_k<<<NSRC * 64 / 256, 256, 0, stream>>>(C, vv, u);
      colsum_f32_k<<<dim3(8, 128), 256, 0, stream>>>(C, u, c);
      finishv_k<<<NTGT / 256, 256, 0, stream>>>(c, vv);
    }
    coupling_f32_k<<<8192, 256, 0, stream>>>(C, u, vv, partials);
    finalize_k<<<1, 256, 0, stream>>>(partials, out, 8192, -0.1f);
  }
}

// Round 10
// 686.077 us; speedup vs baseline: 1.2545x; 1.0526x over previous
//
#include <hip/hip_runtime.h>
#include <hip/hip_bf16.h>
#include <math.h>

#define NSRC 8192
#define NTGT 8192
#define DIM 64

typedef short bf16x8 __attribute__((ext_vector_type(8)));
typedef float f32x16 __attribute__((ext_vector_type(16)));

// ---------------------------------------------------------------------------
// helpers
// ---------------------------------------------------------------------------
__device__ __forceinline__ float wave_reduce_sum(float x) {
#pragma unroll
  for (int off = 32; off > 0; off >>= 1) x += __shfl_down(x, off, 64);
  return x;
}

__device__ __forceinline__ float bflo(unsigned int u) {  // low bf16 of a u32
  return __uint_as_float(u << 16);
}
__device__ __forceinline__ float bfhi(unsigned int u) {  // high bf16 of a u32
  return __uint_as_float(u & 0xFFFF0000u);
}
__device__ __forceinline__ unsigned short f2bfr(float x) {
  __hip_bfloat16 b = __float2bfloat16(x);
  return __hip_bfloat16_raw(b).x;
}

// ---------------------------------------------------------------------------
// kernel 1: squared norms of source rows and target rows (f32 inputs)
// ---------------------------------------------------------------------------
__global__ __launch_bounds__(256) void norms_k(const float* __restrict__ S,
                                               const float* __restrict__ T,
                                               float* __restrict__ s2,
                                               float* __restrict__ t2) {
  int i = blockIdx.x * 256 + threadIdx.x;
  if (i >= NSRC + NTGT) return;
  const float* base = (i < NSRC) ? (S + (size_t)i * DIM)
                                 : (T + (size_t)(i - NSRC) * DIM);
  const float4* p = (const float4*)base;
  float a = 0.f;
#pragma unroll
  for (int k = 0; k < DIM / 4; ++k) {
    float4 v = p[k];
    a += v.x * v.x + v.y * v.y + v.z * v.z + v.w * v.w;
  }
  if (i < NSRC) s2[i] = a;
  else          t2[i - NSRC] = a;
}

// ---------------------------------------------------------------------------
// kernel 1b: split features into bf16 hi + bf16 lo (lo = x - float(hi)).
// ---------------------------------------------------------------------------
__global__ __launch_bounds__(256) void prep_k(const float* __restrict__ S,
                                              const float* __restrict__ T,
                                              unsigned short* __restrict__ Shi,
                                              unsigned short* __restrict__ Slo,
                                              unsigned short* __restrict__ Thi,
                                              unsigned short* __restrict__ Tlo) {
  int i = blockIdx.x * 256 + threadIdx.x;
  const float* src;
  unsigned short *dh, *dl;
  if (i < 65536) { src = S; dh = Shi; dl = Slo; }
  else { src = T; dh = Thi; dl = Tlo; i -= 65536; }
  const float4* p = (const float4*)(src + (size_t)i * 8);
  float4 x = p[0], y = p[1];
  float vals[8] = {x.x, x.y, x.z, x.w, y.x, y.y, y.z, y.w};
  unsigned int h[8], lo[8];
#pragma unroll
  for (int e = 0; e < 8; ++e) {
    unsigned short hr = f2bfr(vals[e]);
    h[e] = hr;
    lo[e] = f2bfr(vals[e] - bflo(hr));
  }
  uint4 hw = make_uint4(h[0] | (h[1] << 16), h[2] | (h[3] << 16),
                        h[4] | (h[5] << 16), h[6] | (h[7] << 16));
  uint4 lw = make_uint4(lo[0] | (lo[1] << 16), lo[2] | (lo[3] << 16),
                        lo[4] | (lo[5] << 16), lo[6] | (lo[7] << 16));
  *(uint4*)(dh + (size_t)i * 8) = hw;
  *(uint4*)(dl + (size_t)i * 8) = lw;
}

// ---------------------------------------------------------------------------
// kernel 2: per-call init. v=1; c=0 (fallback colsum accumulator).
// ---------------------------------------------------------------------------
__global__ __launch_bounds__(256) void init_k(float* __restrict__ c,
                                              float* __restrict__ v_out) {
  int i = blockIdx.x * 256 + threadIdx.x;
  if (i < NTGT) {
    c[i] = 0.f;
    v_out[i] = 1.f;
  }
}

// ---------------------------------------------------------------------------
// kernel 3 (main): MFMA K-build. 64x64 tile/block, 4 waves each 32x32.
// dot = S·T^T via 3 MFMAs per k-step (hi·hi + hi·lo + lo·hi, f32 accum).
// Epilogue: K = exp(-10*sqrt(max(s2+t2-2dot,0))) -> bf16 staged in LDS with
// row-bit-swap swizzle PR(r), then coalesced Kb write + transposed KbT write
// + deterministic per-tile row-sum fold (first u-pass, v==1) into
// rowpart[bn][8192]. No atomics.
// ---------------------------------------------------------------------------
#define PR(r) ((((r) >> 3) + (((r)&7) << 3)))

__global__ __launch_bounds__(256) void kbuild_mfma_k(
    const unsigned short* __restrict__ Shi, const unsigned short* __restrict__ Slo,
    const unsigned short* __restrict__ Thi, const unsigned short* __restrict__ Tlo,
    const float* __restrict__ s2, const float* __restrict__ t2,
    __hip_bfloat16* __restrict__ Kb, __hip_bfloat16* __restrict__ KbT,
    float* __restrict__ rowpart) {
  __shared__ unsigned short sAh[64][72], sAl[64][72];
  __shared__ unsigned short sBh[64][72], sBl[64][72];
  __shared__ unsigned short stage[64][72];
  __shared__ float sS2[64], sT2[64];

  const int tid = threadIdx.x;
  const int bm = blockIdx.y * 64, bn = blockIdx.x * 64;

#pragma unroll
  for (int p = 0; p < 2; ++p) {
    int f = tid + 256 * p;
    int row = f >> 3, seg = (f & 7) * 8;
    *(uint4*)&sAh[row][seg] = ((const uint4*)(Shi + (size_t)bm * DIM))[f];
    *(uint4*)&sAl[row][seg] = ((const uint4*)(Slo + (size_t)bm * DIM))[f];
    *(uint4*)&sBh[row][seg] = ((const uint4*)(Thi + (size_t)bn * DIM))[f];
    *(uint4*)&sBl[row][seg] = ((const uint4*)(Tlo + (size_t)bn * DIM))[f];
  }
  if (tid < 64) sS2[tid] = s2[bm + tid];
  else if (tid < 128) sT2[tid - 64] = t2[bn + (tid - 64)];
  __syncthreads();

  const int w = tid >> 6, l = tid & 63;
  const int wr = w >> 1, wc = w & 1;
  const int arow = 32 * wr + (l & 31);
  const int brow = 32 * wc + (l & 31);
  const int kh = 8 * (l >> 5);

  f32x16 acc;
#pragma unroll
  for (int i = 0; i < 16; ++i) acc[i] = 0.f;

#pragma unroll
  for (int ks = 0; ks < 4; ++ks) {
    int ko = 16 * ks + kh;
    bf16x8 ah = *(const bf16x8*)&sAh[arow][ko];
    bf16x8 al = *(const bf16x8*)&sAl[arow][ko];
    bf16x8 bh = *(const bf16x8*)&sBh[brow][ko];
    bf16x8 bl = *(const bf16x8*)&sBl[brow][ko];
    acc = __builtin_amdgcn_mfma_f32_32x32x16_bf16(ah, bh, acc, 0, 0, 0);
    acc = __builtin_amdgcn_mfma_f32_32x32x16_bf16(ah, bl, acc, 0, 0, 0);
    acc = __builtin_amdgcn_mfma_f32_32x32x16_bf16(al, bh, acc, 0, 0, 0);
  }

  // epilogue -> swizzled LDS stage (bf16)
#pragma unroll
  for (int j = 0; j < 16; ++j) {
    int rl = (j & 3) + 8 * (j >> 2) + 4 * (l >> 5);
    int row = 32 * wr + rl, col = 32 * wc + (l & 31);
    float sq = sS2[row] + sT2[col] - 2.f * acc[j];
    float kv = __expf(-10.f * sqrtf(fmaxf(sq, 0.f)));
    stage[PR(row)][col] = f2bfr(kv);
  }
  __syncthreads();

  // fold first u-pass: deterministic per-tile row sums -> rowpart[bn][row]
  {
    int row = tid >> 2, q = tid & 3;
    float a = 0.f;
#pragma unroll
    for (int m = 0; m < 16; ++m)
      a += bflo((unsigned int)stage[PR(row)][16 * q + m]);
    a += __shfl_down(a, 1, 4);
    a += __shfl_down(a, 2, 4);
    if (q == 0) rowpart[(size_t)blockIdx.x * NSRC + bm + row] = a;
  }

  // Kb write (row-major)
#pragma unroll
  for (int p = 0; p < 2; ++p) {
    int f = tid + 256 * p;
    int row = f >> 3, seg = (f & 7) * 8;
    *(uint4*)(Kb + (size_t)(bm + row) * NTGT + bn + seg) =
        *(const uint4*)&stage[PR(row)][seg];
  }
  // KbT write (transposed): thread owns (source col tcol, 8-row group gro)
#pragma unroll
  for (int p = 0; p < 2; ++p) {
    int f = tid + 256 * p;
    int tcol = f >> 3, gro = f & 7;
    unsigned int wds[4];
#pragma unroll
    for (int e = 0; e < 4; ++e) {
      unsigned int a0 = stage[gro + 8 * (2 * e)][tcol];
      unsigned int a1 = stage[gro + 8 * (2 * e + 1)][tcol];
      wds[e] = a0 | (a1 << 16);
    }
    *(uint4*)(KbT + (size_t)(bn + tcol) * NSRC + bm + 8 * gro) =
        make_uint4(wds[0], wds[1], wds[2], wds[3]);
  }
}

// ---------------------------------------------------------------------------
// kernel 3b: u[i] = sw / (sum_bn rowpart[bn][i] + stab)
// ---------------------------------------------------------------------------
__global__ __launch_bounds__(256) void initu_k(const float* __restrict__ rowpart,
                                               float* __restrict__ u) {
  int i = blockIdx.x * 256 + threadIdx.x;
  float a = 0.f;
#pragma unroll 8
  for (int bn = 0; bn < 128; ++bn) a += rowpart[(size_t)bn * NSRC + i];
  u[i] = (1.0f / NSRC) / (a + 1e-8f);
}

// ---------------------------------------------------------------------------
// kernel 4: y[r] = (1/8192) / (sum_j P[r][j]*x[j] + 1e-8). One wave/row,
// 2048 blocks (32 waves/CU). Used for both Kb (->u) and KbT (->v).
// ---------------------------------------------------------------------------
__global__ __launch_bounds__(256) void rowsum_k(const unsigned short* __restrict__ P,
                                                const float* __restrict__ x,
                                                float* __restrict__ y) {
  int row = blockIdx.x * 4 + (threadIdx.x >> 6);
  int lane = threadIdx.x & 63;
  const uint4* r4 = (const uint4*)(P + (size_t)row * NTGT);
  const float4* x4 = (const float4*)x;
  float a = 0.f;
#pragma unroll 4
  for (int s = lane; s < NTGT / 8; s += 64) {
    uint4 q = r4[s];
    float4 xa = x4[2 * s], xb = x4[2 * s + 1];
    a += bflo(q.x) * xa.x + bfhi(q.x) * xa.y
       + bflo(q.y) * xa.z + bfhi(q.y) * xa.w
       + bflo(q.z) * xb.x + bfhi(q.z) * xb.y
       + bflo(q.w) * xb.z + bfhi(q.w) * xb.w;
  }
  a = wave_reduce_sum(a);
  if (lane == 0) y[row] = (1.0f / 8192.0f) / (a + 1e-8f);
}

// ---------------------------------------------------------------------------
// kernel C: coupling C = u*Kb*v (f32), dist partials via cost = -0.1*ln(Kb).
// Guard ln against bf16 underflow (coupling is 0 there anyway). Overwrites
// the C region (which held KbT — dead by now); float4 stores, proven 73 us.
// ---------------------------------------------------------------------------
__global__ __launch_bounds__(256) void coupling_bf16_k(
    const unsigned short* __restrict__ Kb,
    const float* __restrict__ u,
    const float* __restrict__ v,
    float* __restrict__ C,
    float* __restrict__ partials) {
  __shared__ float red[4];
  size_t g = (size_t)blockIdx.x * 256 + threadIdx.x;
  size_t base = g * 32;
  int i = (int)(base >> 13);
  int j0 = (int)(base & 8191);
  float ui = u[i];
  const uint4* kp = (const uint4*)(Kb + base);
  const float4* vp = (const float4*)(v + j0);
  float part = 0.f;
#pragma unroll
  for (int s = 0; s < 4; ++s) {
    uint4 q = kp[s];
    float4 va = vp[2 * s], vb = vp[2 * s + 1];
    float k0 = bflo(q.x), k1 = bfhi(q.x), k2 = bflo(q.y), k3 = bfhi(q.y);
    float k4 = bflo(q.z), k5 = bfhi(q.z), k6 = bflo(q.w), k7 = bfhi(q.w);
    float c0 = ui * k0 * va.x, c1 = ui * k1 * va.y;
    float c2 = ui * k2 * va.z, c3 = ui * k3 * va.w;
    float c4 = ui * k4 * vb.x, c5 = ui * k5 * vb.y;
    float c6 = ui * k6 * vb.z, c7 = ui * k7 * vb.w;
    part += c0 * __logf(fmaxf(k0, 1e-37f)) + c1 * __logf(fmaxf(k1, 1e-37f)) +
            c2 * __logf(fmaxf(k2, 1e-37f)) + c3 * __logf(fmaxf(k3, 1e-37f)) +
            c4 * __logf(fmaxf(k4, 1e-37f)) + c5 * __logf(fmaxf(k5, 1e-37f)) +
            c6 * __logf(fmaxf(k6, 1e-37f)) + c7 * __logf(fmaxf(k7, 1e-37f));
    float* cw = C + base + 8 * s;
    *(float4*)cw       = make_float4(c0, c1, c2, c3);
    *(float4*)(cw + 4) = make_float4(c4, c5, c6, c7);
  }
  part = wave_reduce_sum(part);
  int wid = threadIdx.x >> 6, lane = threadIdx.x & 63;
  if (lane == 0) red[wid] = part;
  __syncthreads();
  if (threadIdx.x == 0)
    partials[blockIdx.x] = red[0] + red[1] + red[2] + red[3];
}

// ---------------------------------------------------------------------------
// fallback kernels (f32 path; only if ws too small for main path)
// ---------------------------------------------------------------------------
#define BM 64
#define BN 128
__global__ __launch_bounds__(256) void kbuild_k(const float* __restrict__ S,
                                                const float* __restrict__ T,
                                                const float* __restrict__ s2,
                                                const float* __restrict__ t2,
                                                float* __restrict__ Kf) {
  __shared__ float sT[BM][68];
  __shared__ float tT[BN][68];
  const int bn = blockIdx.x * BN;
  const int bm = blockIdx.y * BM;
  const int tid = threadIdx.x;
  {
    const float4* sg = (const float4*)(S + (size_t)bm * DIM);
#pragma unroll
    for (int k = 0; k < 4; ++k) {
      int f = tid + 256 * k;
      int row = f >> 4, c4 = f & 15;
      *(float4*)&sT[row][c4 * 4] = sg[f];
    }
    const float4* tg = (const float4*)(T + (size_t)bn * DIM);
#pragma unroll
    for (int k = 0; k < 8; ++k) {
      int f = tid + 256 * k;
      int row = f >> 4, c4 = f & 15;
      *(float4*)&tT[row][c4 * 4] = tg[f];
    }
  }
  __syncthreads();
  const int tx = tid & 15;
  const int ty = tid >> 4;
  float acc[4][8];
#pragma unroll
  for (int a = 0; a < 4; ++a)
#pragma unroll
    for (int b = 0; b < 8; ++b) acc[a][b] = 0.f;
  for (int k = 0; k < DIM; k += 4) {
    float4 sr[4], trg[8];
#pragma unroll
    for (int a = 0; a < 4; ++a) sr[a] = *(float4*)&sT[ty + 16 * a][k];
#pragma unroll
    for (int b = 0; b < 8; ++b) trg[b] = *(float4*)&tT[tx + 16 * b][k];
#pragma unroll
    for (int a = 0; a < 4; ++a)
#pragma unroll
      for (int b = 0; b < 8; ++b) {
        acc[a][b] += sr[a].x * trg[b].x;
        acc[a][b] += sr[a].y * trg[b].y;
        acc[a][b] += sr[a].z * trg[b].z;
        acc[a][b] += sr[a].w * trg[b].w;
      }
  }
#pragma unroll
  for (int a = 0; a < 4; ++a) {
    int gi = bm + ty + 16 * a;
    float s2v = s2[gi];
#pragma unroll
    for (int b = 0; b < 8; ++b) {
      int gj = bn + tx + 16 * b;
      float sq = s2v + t2[gj] - 2.f * acc[a][b];
      float cost = sqrtf(fmaxf(sq, 0.f));
      Kf[(size_t)gi * NTGT + gj] = __expf(-10.f * cost);
    }
  }
}

__global__ __launch_bounds__(256) void rowsum_f32_k(const float* __restrict__ K,
                                                    const float* __restrict__ v,
                                                    float* __restrict__ u_out) {
  int row = (blockIdx.x * 256 + threadIdx.x) >> 6;
  int lane = threadIdx.x & 63;
  const float4* r4 = (const float4*)(K + (size_t)row * NTGT);
  const float4* v4 = (const float4*)v;
  float a = 0.f;
#pragma unroll 4
  for (int j = lane; j < NTGT / 4; j += 64) {
    float4 k4 = r4[j];
    float4 vv = v4[j];
    a += k4.x * vv.x + k4.y * vv.y + k4.z * vv.z + k4.w * vv.w;
  }
  a = wave_reduce_sum(a);
  if (lane == 0) u_out[row] = (1.0f / NSRC) / (a + 1e-8f);
}

__global__ __launch_bounds__(256) void colsum_f32_k(const float* __restrict__ K,
                                                    const float* __restrict__ u,
                                                    float* __restrict__ c) {
  int j = blockIdx.x * 1024 + threadIdx.x * 4;
  int i0 = blockIdx.y * 64;
  float a0 = 0.f, a1 = 0.f, a2 = 0.f, a3 = 0.f;
#pragma unroll 8
  for (int i = i0; i < i0 + 64; ++i) {
    float ui = u[i];
    float4 k4 = *(const float4*)(K + (size_t)i * NTGT + j);
    a0 += k4.x * ui; a1 += k4.y * ui; a2 += k4.z * ui; a3 += k4.w * ui;
  }
  atomicAdd(&c[j + 0], a0);
  atomicAdd(&c[j + 1], a1);
  atomicAdd(&c[j + 2], a2);
  atomicAdd(&c[j + 3], a3);
}

__global__ __launch_bounds__(256) void finishv_k(float* __restrict__ c,
                                                 float* __restrict__ v_out) {
  int j = blockIdx.x * 256 + threadIdx.x;
  v_out[j] = (1.0f / NTGT) / (c[j] + 1e-8f);
  c[j] = 0.f;
}

__global__ __launch_bounds__(256) void coupling_f32_k(float* __restrict__ K,
                                                      const float* __restrict__ u,
                                                      const float* __restrict__ v,
                                                      float* __restrict__ partials) {
  __shared__ float red[4];
  size_t t0 = (size_t)blockIdx.x * 2048 + threadIdx.x;
  float part = 0.f;
#pragma unroll
  for (int s = 0; s < 8; ++s) {
    size_t f4 = t0 + (size_t)s * 256;
    size_t base = f4 * 4;
    int i = (int)(base >> 13);
    int j = (int)(base & 8191);
    float4 k4 = *(float4*)(K + base);
    float ui = u[i];
    float4 vv = *(const float4*)(v + j);
    float c0 = ui * k4.x * vv.x;
    float c1 = ui * k4.y * vv.y;
    float c2 = ui * k4.z * vv.z;
    float c3 = ui * k4.w * vv.w;
    part += c0 * __logf(k4.x) + c1 * __logf(k4.y) +
            c2 * __logf(k4.z) + c3 * __logf(k4.w);
    *(float4*)(K + base) = make_float4(c0, c1, c2, c3);
  }
  part = wave_reduce_sum(part);
  int wid = threadIdx.x >> 6, lane = threadIdx.x & 63;
  if (lane == 0) red[wid] = part;
  __syncthreads();
  if (threadIdx.x == 0)
    partials[blockIdx.x] = red[0] + red[1] + red[2] + red[3];
}

// ---------------------------------------------------------------------------
// kernel 8: dist = scale * sum(partials)/(ns*nt); log-based partials use
// scale = -0.1 (eps).
// ---------------------------------------------------------------------------
__global__ __launch_bounds__(256) void finalize_k(const float* __restrict__ partials,
                                                  float* __restrict__ out,
                                                  int npart, float scale) {
  __shared__ float red[4];
  float a = 0.f;
  for (int i = threadIdx.x; i < npart; i += 256) a += partials[i];
  a = wave_reduce_sum(a);
  int wid = threadIdx.x >> 6, lane = threadIdx.x & 63;
  if (lane == 0) red[wid] = a;
  __syncthreads();
  if (threadIdx.x == 0)
    out[0] = (red[0] + red[1] + red[2] + red[3]) *
             (scale / ((float)NSRC * (float)NTGT));
}

// ---------------------------------------------------------------------------
extern "C" void kernel_launch(void* const* d_in, const int* in_sizes, int n_in,
                              void* d_out, int out_size, void* d_ws, size_t ws_size,
                              hipStream_t stream) {
  const float* S = (const float*)d_in[0];
  const float* T = (const float*)d_in[1];
  float* out = (float*)d_out;

  // output layout: [dist(1)][coupling(64M)][u(8192)][v(8192)]
  float* C  = out + 1;
  float* u  = out + 1 + (size_t)NSRC * NTGT;
  float* vv = u + NSRC;

  // KbT lives in the C region during the iterations (dead until coupling;
  // coupling_bf16 overwrites every element). +4B base: dword-aligned, proven.
  __hip_bfloat16* KbT = (__hip_bfloat16*)C;

  // ws byte layout (total = 16M + 128M = 144 MB; proven round 3):
  //   s2 @0(32K) t2 @32K c @64K(32K, fallback) partials @128K(32K)
  //   rowpart @1M (4 MB)
  //   Shi @6M Slo @7M Thi @8M Tlo @9M (1 MB each)
  //   Kb @16M (128 MB)
  char* wsb = (char*)d_ws;
  float* s2       = (float*)(wsb);
  float* t2       = (float*)(wsb + (32 << 10));
  float* c        = (float*)(wsb + (64 << 10));
  float* partials = (float*)(wsb + (128 << 10));
  float* rowpart  = (float*)(wsb + (1 << 20));
  unsigned short* Shi = (unsigned short*)(wsb + ((size_t)6 << 20));
  unsigned short* Slo = (unsigned short*)(wsb + ((size_t)7 << 20));
  unsigned short* Thi = (unsigned short*)(wsb + ((size_t)8 << 20));
  unsigned short* Tlo = (unsigned short*)(wsb + ((size_t)9 << 20));
  const size_t KB_OFF = (size_t)16 << 20;
  const size_t KB_BYTES = (size_t)NSRC * NTGT * 2;  // 128 MB
  __hip_bfloat16* Kb = (__hip_bfloat16*)(wsb + KB_OFF);

  bool full = ws_size >= KB_OFF + KB_BYTES;

  norms_k<<<(NSRC + NTGT + 255) / 256, 256, 0, stream>>>(S, T, s2, t2);

  if (full) {
    prep_k<<<512, 256, 0, stream>>>(S, T, Shi, Slo, Thi, Tlo);
    kbuild_mfma_k<<<dim3(128, 128), 256, 0, stream>>>(
        Shi, Slo, Thi, Tlo, s2, t2, Kb, KbT, rowpart);
    initu_k<<<NSRC / 256, 256, 0, stream>>>(rowpart, u);
    // iteration 1's v needs v=1 only implicitly (u folded above); set v via
    // first KbT pass directly.
    for (int it = 0; it < 10; ++it) {
      if (it > 0)
        rowsum_k<<<NSRC / 4, 256, 0, stream>>>((const unsigned short*)Kb, vv, u);
      rowsum_k<<<NTGT / 4, 256, 0, stream>>>((const unsigned short*)KbT, u, vv);
    }
    coupling_bf16_k<<<8192, 256, 0, stream>>>(
        (const unsigned short*)Kb, u, vv, C, partials);
    finalize_k<<<1, 256, 0, stream>>>(partials, out, 8192, -0.1f);
  } else {
    init_k<<<NTGT / 256, 256, 0, stream>>>(c, vv);
    kbuild_k<<<dim3(NTGT / BN, NSRC / BM), 256, 0, stream>>>(S, T, s2, t2, C);
    for (int it = 0; it < 10; ++it) {
      rowsum_f32_k<<<NSRC * 64 / 256, 256, 0, stream>>>(C, vv, u);
      colsum_f32_k<<<dim3(8, 128), 256, 0, stream>>>(C, u, c);
      finishv_k<<<NTGT / 256, 256, 0, stream>>>(c, vv);
    }
    coupling_f32_k<<<8192, 256, 0, stream>>>(C, u, vv, partials);
    finalize_k<<<1, 256, 0, stream>>>(partials, out, 8192, -0.1f);
  }
}